// Round 10
// baseline (230.833 us; speedup 1.0000x reference)
//
#include <hip/hip_runtime.h>
#include <hip/hip_bf16.h>

typedef unsigned short u16;
typedef unsigned int u32;
typedef __attribute__((ext_vector_type(8))) short short8;   // 8 bf16 (4 VGPRs) MFMA operand
typedef __attribute__((ext_vector_type(4))) float f32x4;    // MFMA 16x16 accumulator

#define T_TOK 32768
#define SCALE_ATT 0.17677669529663687f   // 32^-0.5

__device__ __forceinline__ u16 f2bf(float f){
  u32 u = __float_as_uint(f);
  u32 r = u + 0x7fffu + ((u >> 16) & 1u);   // RTN-even
  return (u16)(r >> 16);
}
__device__ __forceinline__ float bf2f(u16 h){
  return __uint_as_float(((u32)h) << 16);
}

// XCD-chunked bijective block swizzle (nwg % 8 == 0): consecutive logical
// blocks land on the SAME XCD so shared operand panels hit its private L2.
__device__ __forceinline__ int xcd_swz(int flat, int nwg){
  return (flat & 7) * (nwg >> 3) + (flat >> 3);
}

// async global->LDS, 16B per lane. Dest = wave-uniform base + lane*16 (HW rule,
// m104/m108); global src is per-lane.
__device__ __forceinline__ void gl16(const u16* g, u16* l){
  __builtin_amdgcn_global_load_lds(
      (const __attribute__((address_space(1))) u32*)g,
      (__attribute__((address_space(3))) u32*)l, 16, 0, 0);
}

// ---------------- tiny prep: w1 fp32 -> (hi,lo) bf16 split, ONCE ------------
__global__ __launch_bounds__(256) void k_prep_w1(
    const float* __restrict__ rw1, u16* __restrict__ w1h, u16* __restrict__ w1l)
{
  int i = blockIdx.x * 256 + threadIdx.x;       // < 8192 float4
  float4 v = ((const float4*)rw1)[i];
  ushort4 h, l;
  h.x = f2bf(v.x); h.y = f2bf(v.y); h.z = f2bf(v.z); h.w = f2bf(v.w);
  l.x = f2bf(v.x - bf2f(h.x)); l.y = f2bf(v.y - bf2f(h.y));
  l.z = f2bf(v.z - bf2f(h.z)); l.w = f2bf(v.w - bf2f(h.w));
  ((ushort4*)w1h)[i] = h;
  ((ushort4*)w1l)[i] = l;
}

// ---------------- MFMA router (split-bf16 "bf16x3") + fused weight cvt ------
// blocks [0,512): router (R13/R15). blocks [512,2048+512): weight cvt.
// R18: proj_w is converted into MFMA-FRAGMENT-PERMUTED layout so the fused
// attn+proj kernel loads B as dense 1KB wave accesses:
//   dst_u16(e,n,k) = ((((e*8+kt)*16+nf)*16+l16)*4+quad)*8 + (k&7)
//   with kt=k>>5, quad=(k>>3)&3, nf=n>>4, l16=n&15.
__global__ __launch_bounds__(256) void k_router(
    const float* __restrict__ x, const u16* __restrict__ w1h, const u16* __restrict__ w1l,
    const float* __restrict__ b1, const float* __restrict__ w2, const float* __restrict__ b2,
    int* __restrict__ routes, float* __restrict__ pmax, int* __restrict__ hist,
    u16* __restrict__ x_bf,
    const float* __restrict__ qkvw, u16* __restrict__ qw_bf,
    const float* __restrict__ projw, u16* __restrict__ pw_bf)
{
  __shared__ __align__(16) char smem[64*132*4];   // 33792 B
  int tid = threadIdx.x;

  if (blockIdx.x >= 512){                 // ---- weight cvt section ----
    int b = blockIdx.x - 512;
    if (b < 1536){
      int i = b * 256 + tid;                       // < 393216 float4
      float4 v = ((const float4*)qkvw)[i];
      ushort4 o;
      o.x = f2bf(v.x); o.y = f2bf(v.y); o.z = f2bf(v.z); o.w = f2bf(v.w);
      ((ushort4*)qw_bf)[i] = o;
    } else {
      int i = (b - 1536) * 256 + tid;              // < 131072 float4
      float4 v = ((const float4*)projw)[i];
      ushort4 o;
      o.x = f2bf(v.x); o.y = f2bf(v.y); o.z = f2bf(v.z); o.w = f2bf(v.w);
      int f = i * 4;                               // (e, n, k) flat
      int e  = f >> 16;
      int n  = (f >> 8) & 255;
      int k  = f & 255;                            // multiple of 4
      int kt = k >> 5, quad = (k >> 3) & 3, el = k & 7;
      int nf = n >> 4, l16 = n & 15;
      size_t dst = ((((size_t)(e*8 + kt)*16 + nf)*16 + l16)*4 + quad)*8 + el;
      *(ushort4*)&pw_bf[dst] = o;                  // el in {0,4}: stays in group
    }
    return;
  }

  u16* Ah = (u16*)smem;          // 64 x 40
  u16* Al = Ah + 2560;           // 64 x 40
  u16* Bh = Al + 2560;           // 128 x 40
  u16* Bl = Bh + 5120;           // 128 x 40
  float* Hs = (float*)smem;      // overlay after MFMA: 64 x 132
  __shared__ int lhist[8];

  int t0 = blockIdx.x * 64;
  int wv = tid >> 6, lane = tid & 63, quad = lane >> 4, l16 = lane & 15;
  if (tid < 8) lhist[tid] = 0;

  int arow = tid >> 2, acg = tid & 3;        // A staging: 64 rows x 4 col-groups of 8
  int brow = tid >> 1, bhalf = tid & 1;      // B staging: 128 rows x 2 halves of 16

  f32x4 acc[4][2];
  #pragma unroll
  for (int i = 0; i < 4; ++i)
    #pragma unroll
    for (int j = 0; j < 2; ++j)
      #pragma unroll
      for (int rr = 0; rr < 4; ++rr) acc[i][j][rr] = 0.f;

  const float* gx_base = x + (size_t)(t0 + arow) * 256 + acg * 8;
  u16* gxb_base = x_bf + (size_t)(t0 + arow) * 256 + acg * 8;
  const u16* gwh_base = w1h + (size_t)brow * 256 + bhalf * 16;
  const u16* gwl_base = w1l + (size_t)brow * 256 + bhalf * 16;

  // prologue: loads for kt=0
  float4 v0 = *(const float4*)gx_base;
  float4 v1 = *(const float4*)(gx_base + 4);
  uint4 wh0 = *(const uint4*)(gwh_base);
  uint4 wh1 = *(const uint4*)(gwh_base + 8);
  uint4 wl0 = *(const uint4*)(gwl_base);
  uint4 wl1 = *(const uint4*)(gwl_base + 8);

  for (int kt = 0; kt < 8; ++kt){
    ushort4 h0, h1, l0, l1;
    h0.x = f2bf(v0.x); h0.y = f2bf(v0.y); h0.z = f2bf(v0.z); h0.w = f2bf(v0.w);
    h1.x = f2bf(v1.x); h1.y = f2bf(v1.y); h1.z = f2bf(v1.z); h1.w = f2bf(v1.w);
    l0.x = f2bf(v0.x - bf2f(h0.x)); l0.y = f2bf(v0.y - bf2f(h0.y));
    l0.z = f2bf(v0.z - bf2f(h0.z)); l0.w = f2bf(v0.w - bf2f(h0.w));
    l1.x = f2bf(v1.x - bf2f(h1.x)); l1.y = f2bf(v1.y - bf2f(h1.y));
    l1.z = f2bf(v1.z - bf2f(h1.z)); l1.w = f2bf(v1.w - bf2f(h1.w));
    *(ushort4*)(gxb_base + kt*32)     = h0;
    *(ushort4*)(gxb_base + kt*32 + 4) = h1;
    __syncthreads();
    *(ushort4*)&Ah[arow*40 + acg*8    ] = h0;
    *(ushort4*)&Ah[arow*40 + acg*8 + 4] = h1;
    *(ushort4*)&Al[arow*40 + acg*8    ] = l0;
    *(ushort4*)&Al[arow*40 + acg*8 + 4] = l1;
    *(uint4*)&Bh[brow*40 + bhalf*16    ] = wh0;
    *(uint4*)&Bh[brow*40 + bhalf*16 + 8] = wh1;
    *(uint4*)&Bl[brow*40 + bhalf*16    ] = wl0;
    *(uint4*)&Bl[brow*40 + bhalf*16 + 8] = wl1;
    __syncthreads();
    if (kt < 7){                       // prefetch kt+1: latency hides under MFMA
      v0  = *(const float4*)(gx_base + (kt+1)*32);
      v1  = *(const float4*)(gx_base + (kt+1)*32 + 4);
      wh0 = *(const uint4*)(gwh_base + (kt+1)*32);
      wh1 = *(const uint4*)(gwh_base + (kt+1)*32 + 8);
      wl0 = *(const uint4*)(gwl_base + (kt+1)*32);
      wl1 = *(const uint4*)(gwl_base + (kt+1)*32 + 8);
    }
    short8 ah[4], al[4], bhf[2], blf[2];
    #pragma unroll
    for (int i = 0; i < 4; ++i){
      ah[i] = *(const short8*)&Ah[(i*16 + l16)*40 + quad*8];
      al[i] = *(const short8*)&Al[(i*16 + l16)*40 + quad*8];
    }
    #pragma unroll
    for (int j = 0; j < 2; ++j){
      bhf[j] = *(const short8*)&Bh[(wv*32 + j*16 + l16)*40 + quad*8];
      blf[j] = *(const short8*)&Bl[(wv*32 + j*16 + l16)*40 + quad*8];
    }
    #pragma unroll
    for (int i = 0; i < 4; ++i)
      #pragma unroll
      for (int j = 0; j < 2; ++j){
        acc[i][j] = __builtin_amdgcn_mfma_f32_16x16x32_bf16(ah[i], bhf[j], acc[i][j], 0, 0, 0);
        acc[i][j] = __builtin_amdgcn_mfma_f32_16x16x32_bf16(ah[i], blf[j], acc[i][j], 0, 0, 0);
        acc[i][j] = __builtin_amdgcn_mfma_f32_16x16x32_bf16(al[i], bhf[j], acc[i][j], 0, 0, 0);
      }
  }
  __syncthreads();   // all frag reads done before Hs overlay

  #pragma unroll
  for (int i = 0; i < 4; ++i)
    #pragma unroll
    for (int j = 0; j < 2; ++j){
      int col = wv*32 + j*16 + l16;
      float bb = b1[col];
      #pragma unroll
      for (int rr = 0; rr < 4; ++rr){
        float h = acc[i][j][rr] + bb;
        Hs[(i*16 + quad*4 + rr)*132 + col] = h > 0.f ? h : 0.f;
      }
    }
  __syncthreads();

  // logits + softmax: 8 lanes per token (e = tid&7), 32 tokens/pass (fp32)
  #pragma unroll
  for (int pass = 0; pass < 2; ++pass){
    int mtok = (tid >> 3) + pass * 32;
    int e = tid & 7;
    const float4* w2r = (const float4*)(w2 + e * 128);
    float l = b2[e];
    #pragma unroll
    for (int k4 = 0; k4 < 32; ++k4){
      float4 w = w2r[k4];
      int k = k4 * 4;
      l = fmaf(Hs[mtok*132+k  ], w.x, l);
      l = fmaf(Hs[mtok*132+k+1], w.y, l);
      l = fmaf(Hs[mtok*132+k+2], w.z, l);
      l = fmaf(Hs[mtok*132+k+3], w.w, l);
    }
    float mv = l; int mi = e;
    #pragma unroll
    for (int off = 1; off < 8; off <<= 1){
      float ov = __shfl_xor(mv, off, 64);
      int   oi = __shfl_xor(mi, off, 64);
      if (ov > mv || (ov == mv && oi < mi)){ mv = ov; mi = oi; }
    }
    float sum = expf(l - mv);
    #pragma unroll
    for (int off = 1; off < 8; off <<= 1) sum += __shfl_xor(sum, off, 64);
    if (e == 0){
      int t = t0 + mtok;
      routes[t] = mi;
      pmax[t] = 1.0f / sum;
      atomicAdd(&lhist[mi], 1);
    }
  }
  __syncthreads();
  if (tid < 8) hist[blockIdx.x * 8 + tid] = lhist[tid];
}

// ---------------- deterministic scatter (R15; rank dropped in R18) ----------
__global__ __launch_bounds__(256) void k_scatter(
    const int* __restrict__ routes, const int* __restrict__ hist,
    int* __restrict__ sorted, int* __restrict__ offs)
{
  __shared__ int s_tot[8], s_pre[8], so[9], lc[8];
  int tid = threadIdx.x, b = blockIdx.x;
  if (tid < 8){ s_tot[tid] = 0; s_pre[tid] = 0; lc[tid] = 0; }
  __syncthreads();
  int e8 = tid & 7, r0 = tid >> 3;           // 32 rb-strides per expert
  int tot = 0, pre = 0;
  for (int rb = r0; rb < 512; rb += 32){
    int v = hist[rb * 8 + e8];
    tot += v;
    if (rb < b * 4) pre += v;                // router block rb covers tokens [64rb,64rb+64)
  }
  atomicAdd(&s_tot[e8], tot);
  atomicAdd(&s_pre[e8], pre);
  __syncthreads();
  if (tid == 0){
    int o = 0; so[0] = 0;
    #pragma unroll
    for (int e = 0; e < 8; ++e){ o += ((s_tot[e] + 127) >> 7) << 7; so[e+1] = o; }
  }
  __syncthreads();
  int t = b * 256 + tid;
  int e = routes[t];
  int rl = atomicAdd(&lc[e], 1);
  int pos = so[e] + s_pre[e] + rl;
  sorted[pos] = t;
  if (b == 0){
    if (tid < 9) offs[tid] = so[tid];
    #pragma unroll
    for (int e2 = 0; e2 < 8; ++e2)
      for (int i = so[e2] + s_tot[e2] + tid; i < so[e2+1]; i += 256) sorted[i] = -1;
  }
}

// ---------------- grouped MoE QKV GEMM (R6-verified 128x128 skeleton) -------
// 3-buffer counted-vmcnt pipeline; stage groups pinned with sched_barrier(0)
// (R7 lesson). Chunk XOR swizzle -> 0 bank conflicts (verified R4). Epilogue
// applies 2D RoPE, folds SCALE_ATT into Q, writes head-major windowed layout
// [sel][head][win][n][32ch].
template<int NOUT, int NB, int NWG>
__global__ __launch_bounds__(256) void k_gemm(
    const u16* __restrict__ A, const u16* __restrict__ W,
    const float* __restrict__ bias, const int* __restrict__ sidx,
    const int* __restrict__ offs,
    u16* __restrict__ outb)
{
  __shared__ __align__(1024) u16 As[3][4096];   // [buf][row*32 + slot*8], 8KB/buf
  __shared__ __align__(1024) u16 Bs[3][4096];
  int tid = threadIdx.x;
  int flat = blockIdx.y * NB + blockIdx.x;     // hw dispatch order (x fastest)
  int logical = xcd_swz(flat, NWG);
  int m0 = (logical / NB) * 128;
  int n0 = (logical % NB) * 128;
  int total = offs[8];
  if (m0 >= total) return;
  int e = 0;
  #pragma unroll
  for (int i = 1; i < 8; ++i) if (m0 >= offs[i]) e = i;

  int wv = tid >> 6, lane = tid & 63, quad = lane >> 4, l16 = lane & 15;
  int wrow = (wv >> 1) * 64, wcol = (wv & 1) * 64;

  int srow = wv*16 + (lane >> 2);
  int cg = (lane & 3) ^ ((srow >> 1) & 3);     // global chunk to fetch
  int tA0 = sidx[m0 + srow];      if (tA0 < 0) tA0 = 0;   // row discarded in epilogue
  int tA1 = sidx[m0 + srow + 64]; if (tA1 < 0) tA1 = 0;
  const u16* ag0 = A + (size_t)tA0 * 256 + cg * 8;
  const u16* ag1 = A + (size_t)tA1 * 256 + cg * 8;
  int pc = (srow >> 4) + (srow & 15) * 4;      // permuted col within 64-half
  const u16* bg0 = W + ((size_t)e * NOUT + n0 + pc) * 256 + cg * 8;
  const u16* bg1 = W + ((size_t)e * NOUT + n0 + 64 + pc) * 256 + cg * 8;

  f32x4 acc[4][4];
  #pragma unroll
  for (int i = 0; i < 4; ++i)
    #pragma unroll
    for (int j = 0; j < 4; ++j)
      #pragma unroll
      for (int r = 0; r < 4; ++r) acc[i][j][r] = 0.f;

  int qsw8 = (quad ^ ((l16 >> 1) & 3)) * 8;    // swizzled read slot (elems)

#define STAGE_KT(kt, buf) do { \
    u16* a_lo = &As[(buf)][0] + wv*512; \
    u16* b_lo = &Bs[(buf)][0] + wv*512; \
    gl16(ag0 + (kt)*32, a_lo); \
    gl16(ag1 + (kt)*32, a_lo + 2048); \
    gl16(bg0 + (kt)*32, b_lo); \
    gl16(bg1 + (kt)*32, b_lo + 2048); \
  } while(0)

  // prologue: stage kt 0 and 1 (8 loads in flight), groups PINNED
  STAGE_KT(0, 0);
  __builtin_amdgcn_sched_barrier(0);
  STAGE_KT(1, 1);
  __builtin_amdgcn_sched_barrier(0);

  #pragma unroll
  for (int kt = 0; kt < 8; ++kt){
    const int cur = kt % 3;
    if (kt < 7) asm volatile("s_waitcnt vmcnt(4) lgkmcnt(0)" ::: "memory");
    else        asm volatile("s_waitcnt vmcnt(0) lgkmcnt(0)" ::: "memory");
    __builtin_amdgcn_sched_barrier(0);
    __builtin_amdgcn_s_barrier();
    __builtin_amdgcn_sched_barrier(0);
    if (kt < 6){
      STAGE_KT(kt+2, (kt+2)%3);
      __builtin_amdgcn_sched_barrier(0);
    }
    short8 af[4], bfv[4];
    #pragma unroll
    for (int i = 0; i < 4; ++i)
      af[i] = *(const short8*)&As[cur][(wrow + i*16 + l16)*32 + qsw8];
    #pragma unroll
    for (int j = 0; j < 4; ++j)
      bfv[j] = *(const short8*)&Bs[cur][(wcol + j*16 + l16)*32 + qsw8];
    #pragma unroll
    for (int i = 0; i < 4; ++i)
      #pragma unroll
      for (int j = 0; j < 4; ++j)
        acc[i][j] = __builtin_amdgcn_mfma_f32_16x16x32_bf16(af[i], bfv[j], acc[i][j], 0, 0, 0);
  }
#undef STAGE_KT

  // epilogue: frag j of lane l16 = output col n0+wcol+l16*4+j (contiguous)
  float4 bj4 = *(const float4*)&bias[e*NOUT + n0 + wcol + l16*4];
  int col0 = n0 + wcol + l16*4;
  bool isqk = (col0 < 512);
  float inv0 = 0.f, inv1 = 0.f;
  float qsc = (col0 < 256) ? SCALE_ATT : 1.0f;
  if (isqk){
    int p0 = (col0 & 15) >> 1;                    // pair idx within half: 0,2,4,6
    inv0 = __expf(-1.1512925465f * (float)p0);    // 10000^(-p0/8)
    inv1 = inv0 * 0.31622776601683794f;           // * 10^-0.5 -> 10000^(-(p0+1)/8)
  }
  int sel  = col0 >> 8;                            // 0=Q 1=K 2=V
  int head = (col0 >> 5) & 7;
  int ch   = col0 & 31;                            // multiple of 4
  size_t hb = ((size_t)(sel * 8 + head) * 512) * 2048 + ch;
  #pragma unroll
  for (int i = 0; i < 4; ++i){
    #pragma unroll
    for (int ri = 0; ri < 4; ++ri){
      int row = wrow + i*16 + quad*4 + ri;        // C/D: row=quad*4+reg [m89]
      int t = sidx[m0 + row];
      if (t < 0) continue;
      float vx = acc[i][0][ri] + bj4.x;
      float vy = acc[i][1][ri] + bj4.y;
      float vz = acc[i][2][ri] + bj4.z;
      float vw = acc[i][3][ri] + bj4.w;
      if (isqk){
        // token window coords: row half = (t>>6)&7, col half = t&7
        float pos = (float)((col0 & 16) ? (t & 7) : ((t >> 6) & 7));
        float a0r = pos * inv0, a1r = pos * inv1;
        float s0, c0s, s1, c1s;
        __sincosf(a0r, &s0, &c0s);
        __sincosf(a1r, &s1, &c1s);
        float r0 = (vx*c0s - vy*s0) * qsc;
        float r1 = (vx*s0 + vy*c0s) * qsc;
        float r2 = (vz*c1s - vw*s1) * qsc;
        float r3 = (vz*s1 + vw*c1s) * qsc;
        vx = r0; vy = r1; vz = r2; vw = r3;
      }
      // head-major windowed address: win = b*64+wy*8+wx, n = iy*8+ix
      int win = (t >> 12) * 64 + ((t >> 9) & 7) * 8 + ((t >> 3) & 7);
      int n   = ((t >> 6) & 7) * 8 + (t & 7);
      uint2 ov;
      ov.x = (u32)f2bf(vx) | ((u32)f2bf(vy) << 16);
      ov.y = (u32)f2bf(vz) | ((u32)f2bf(vw) << 16);
      *(uint2*)&outb[hb + (size_t)win * 2048 + n * 32] = ov;
    }
  }
}

// ---------------- fused windowed attention + MoE output projection ----------
// R18: one 512-thread block per WINDOW (8 waves = 8 heads). Attention per
// wave as before (head-major qkv, in-reg RoPE'd Q/K, shfl row-sums). O is
// written bf16 to a shared LDS tile O_s[64][256] (XOR-swizzled, overlaying
// the dead Ps/Vt regions), then the SAME block computes the per-token expert
// projection: per-wave 32 output cols, masked per-expert passes (expert set
// from one ballot; bit row of the ballot is the row predicate), B-frags
// loaded dense from the fragment-permuted pw_bf (L2-resident 1MB), bias +
// Switch pmax scaling fused, fp32 stored directly to out. Deletes attn_s
// (34MB traffic), rank[], and the separate proj-GEMM launch.
__global__ __launch_bounds__(512, 1) void k_attn_proj(
    const u16* __restrict__ qkv, const int* __restrict__ routes,
    const float* __restrict__ pmax, const u16* __restrict__ pw,
    const float* __restrict__ projb, float* __restrict__ out)
{
  __shared__ __align__(16) u16 lds[55296];   // 8 x (Ps 4608 + Vt 2304) u16
  __shared__ int er_s[64];
  __shared__ float pm_s[64];

  int tid = threadIdx.x;
  int w = tid >> 6, lane = tid & 63;         // wave = head
  int quad = lane >> 4, l16 = lane & 15;
  u16* Ps = lds + w * 6912;
  u16* Vt = Ps + 4608;
  u16* O_s = lds;                            // overlay after barrier (16384 u16)

  int win = xcd_swz(blockIdx.x, 512);        // 0..511
  int b = win >> 6, wy = (win >> 3) & 7, wx = win & 7;
  int tb = b*4096 + wy*512 + wx*8;           // token(n) = tb + (n>>3)*64 + (n&7)

  // routes/pmax for the window's 64 tokens (early: hidden under QK)
  if (tid < 64){
    int t = tb + (tid >> 3) * 64 + (tid & 7);
    er_s[tid] = routes[t];
    pm_s[tid] = pmax[t];
  }

  const u16* qbase = qkv + (size_t)(w * 512 + win) * 2048;
  const u16* kbase = qbase + (size_t)8 * 512 * 2048;
  const u16* vbase = qbase + (size_t)16 * 512 * 2048;

  // Q/K frags: wave covers 1KB contiguous per load
  short8 qf[4], kf[4];
  #pragma unroll
  for (int i = 0; i < 4; ++i){
    qf[i] = *(const short8*)(qbase + (i*16 + l16)*32 + quad*8);
    kf[i] = *(const short8*)(kbase + (i*16 + l16)*32 + quad*8);
  }
  uint4 va[4];
  #pragma unroll
  for (int h = 0; h < 4; ++h)
    va[h] = *(const uint4*)(vbase + h*512 + l16*32 + quad*8);

  // S = Q K^T (scale folded into Q)
  f32x4 sa[4][4];
  #pragma unroll
  for (int i = 0; i < 4; ++i)
    #pragma unroll
    for (int j = 0; j < 4; ++j){
      #pragma unroll
      for (int rr = 0; rr < 4; ++rr) sa[i][j][rr] = 0.f;
      sa[i][j] = __builtin_amdgcn_mfma_f32_16x16x32_bf16(qf[i], kf[j], sa[i][j], 0, 0, 0);
    }

  // P = exp(S) -> bf16 -> Ps (permuted col); row-sums via shfl over l16
  f32x4 rs[4];
  #pragma unroll
  for (int i = 0; i < 4; ++i)
    #pragma unroll
    for (int rr = 0; rr < 4; ++rr){
      float e0 = __expf(sa[i][0][rr]);
      float e1 = __expf(sa[i][1][rr]);
      float e2 = __expf(sa[i][2][rr]);
      float e3 = __expf(sa[i][3][rr]);
      rs[i][rr] = (e0 + e1) + (e2 + e3);
      uint2 pk;
      pk.x = (u32)f2bf(e0) | ((u32)f2bf(e1) << 16);
      pk.y = (u32)f2bf(e2) | ((u32)f2bf(e3) << 16);
      *(uint2*)&Ps[(i*16 + quad*4 + rr)*72 + l16*4] = pk;
    }
  #pragma unroll
  for (int i = 0; i < 4; ++i)
    #pragma unroll
    for (int rr = 0; rr < 4; ++rr){
      #pragma unroll
      for (int off = 1; off < 16; off <<= 1)
        rs[i][rr] += __shfl_xor(rs[i][rr], off, 64);
    }

  // stage V transposed+permuted: Vt[d][pi(n)] = V[n][d]; pi(n) = l16*4 + h
  u32* vu = (u32*)va;
  #pragma unroll
  for (int h = 0; h < 4; ++h){
    int pn = l16 * 4 + h;
    #pragma unroll
    for (int ww = 0; ww < 4; ++ww){
      u32 vv = vu[h*4 + ww];
      Vt[(quad*8 + 2*ww    )*72 + pn] = (u16)(vv & 0xffff);
      Vt[(quad*8 + 2*ww + 1)*72 + pn] = (u16)(vv >> 16);
    }
  }

  // PV
  f32x4 oa[4][2];
  #pragma unroll
  for (int i = 0; i < 4; ++i)
    #pragma unroll
    for (int rr = 0; rr < 4; ++rr){ oa[i][0][rr] = 0.f; oa[i][1][rr] = 0.f; }
  #pragma unroll
  for (int ks = 0; ks < 2; ++ks){
    short8 vf0 = *(const short8*)&Vt[(     l16)*72 + ks*32 + quad*8];
    short8 vf1 = *(const short8*)&Vt[(16 + l16)*72 + ks*32 + quad*8];
    #pragma unroll
    for (int i = 0; i < 4; ++i){
      short8 pf = *(const short8*)&Ps[(i*16 + l16)*72 + ks*32 + quad*8];
      oa[i][0] = __builtin_amdgcn_mfma_f32_16x16x32_bf16(pf, vf0, oa[i][0], 0, 0, 0);
      oa[i][1] = __builtin_amdgcn_mfma_f32_16x16x32_bf16(pf, vf1, oa[i][1], 0, 0, 0);
    }
  }

  __syncthreads();   // ALL waves done reading Ps/Vt before O_s overlay

  // O -> LDS bf16, swizzled: u16 off = m*256 + (col ^ ((m&7)<<3))
  #pragma unroll
  for (int i = 0; i < 4; ++i)
    #pragma unroll
    for (int rr = 0; rr < 4; ++rr){
      float inv = __builtin_amdgcn_rcpf(rs[i][rr]);
      int m = i*16 + quad*4 + rr;
      int key = (m & 7) << 3;
      int c0 = w*32 + l16;
      O_s[m*256 + (c0 ^ key)]        = f2bf(oa[i][0][rr] * inv);
      O_s[m*256 + ((c0+16) ^ key)]   = f2bf(oa[i][1][rr] * inv);
    }
  __syncthreads();   // O_s complete

  // ---------------- projection: out[t] = O[t] @ W[e[t]]^T + b, * pmax ------
  int e_l = er_s[lane];                      // lane <-> row bijection
  #pragma unroll 1
  for (int eu = 0; eu < 8; ++eu){
    unsigned long long hit = __ballot(e_l == eu);
    if (hit == 0ull) continue;
    float b0 = projb[eu*256 + w*32 + l16];
    float b1 = projb[eu*256 + w*32 + 16 + l16];
    f32x4 acc[4][2];
    #pragma unroll
    for (int i = 0; i < 4; ++i)
      #pragma unroll
      for (int r = 0; r < 4; ++r){ acc[i][0][r] = 0.f; acc[i][1][r] = 0.f; }
    #pragma unroll
    for (int kt = 0; kt < 8; ++kt){
      // B frags: dense 1KB wave loads from fragment-permuted pw
      const u16* bb = pw + ((((size_t)(eu*8 + kt)*16 + w*2)*16 + l16)*4 + quad)*8;
      short8 bf0 = *(const short8*)bb;
      short8 bf1 = *(const short8*)(bb + 512);     // nf=1: +16*4*8 u16
      int ck = (kt*32 + quad*8);
      #pragma unroll
      for (int i = 0; i < 4; ++i){
        int row = i*16 + l16;
        short8 af = *(const short8*)&O_s[row*256 + (ck ^ ((row & 7) << 3))];
        acc[i][0] = __builtin_amdgcn_mfma_f32_16x16x32_bf16(af, bf0, acc[i][0], 0, 0, 0);
        acc[i][1] = __builtin_amdgcn_mfma_f32_16x16x32_bf16(af, bf1, acc[i][1], 0, 0, 0);
      }
    }
    // epilogue: row predicate = bit row of ballot
    #pragma unroll
    for (int i = 0; i < 4; ++i)
      #pragma unroll
      for (int ri = 0; ri < 4; ++ri){
        int row = i*16 + quad*4 + ri;
        if (!((hit >> row) & 1ull)) continue;
        int t = tb + (row >> 3) * 64 + (row & 7);
        float pm = pm_s[row];
        out[(size_t)t * 256 + w*32 + l16]      = (acc[i][0][ri] + b0) * pm;
        out[(size_t)t * 256 + w*32 + 16 + l16] = (acc[i][1][ri] + b1) * pm;
      }
  }
}

// ---------------- launch ----------------
extern "C" void kernel_launch(void* const* d_in, const int* in_sizes, int n_in,
                              void* d_out, int out_size, void* d_ws, size_t ws_size,
                              hipStream_t stream){
  const float* x     = (const float*)d_in[0];
  const float* rw1   = (const float*)d_in[1];
  const float* rb1   = (const float*)d_in[2];
  const float* rw2   = (const float*)d_in[3];
  const float* rb2   = (const float*)d_in[4];
  const float* qkvw  = (const float*)d_in[5];
  const float* qkvb  = (const float*)d_in[6];
  const float* projw = (const float*)d_in[7];
  const float* projb = (const float*)d_in[8];
  float* out = (float*)d_out;

  char* ws = (char*)d_ws;
  u16*   x_bf    = (u16*)(ws);                       // 16,777,216 B
  u16*   qkv_bf  = (u16*)(ws + 16777216);            // 50,331,648 B (head-major windowed)
  u16*   w1h     = (u16*)(ws + 67108864);            //     65,536 B
  u16*   w1l     = w1h + 32768;                      //     65,536 B
  u16*   qw_bf   = (u16*)(ws + 84410368);            //  3,145,728 B
  u16*   pw_bf   = (u16*)(ws + 87556096);            //  1,048,576 B (fragment-permuted)
  int*   routes  = (int*)(ws + 88604672);            //    131,072 B
  float* pmaxp   = (float*)(ws + 88735744);          //    131,072 B
  int*   sorted  = (int*)(ws + 88866816);            //    135,168 B (33792 slots)
  int*   hist    = (int*)(ws + 89133056);            //     16,384 B (512 x 8)
  int*   offs    = (int*)(ws + 89149440);            //         36 B

  k_prep_w1<<<32, 256, 0, stream>>>(rw1, w1h, w1l);
  k_router<<<2560, 256, 0, stream>>>(x, w1h, w1l, rb1, rw2, rb2, routes, pmaxp, hist,
                                     x_bf, qkvw, qw_bf, projw, pw_bf);
  k_scatter<<<128, 256, 0, stream>>>(routes, hist, sorted, offs);
  k_gemm<768, 6, 1584><<<dim3(6, 264), 256, 0, stream>>>(
      x_bf, qw_bf, qkvb, sorted, offs, qkv_bf);
  k_attn_proj<<<512, 512, 0, stream>>>(qkv_bf, routes, pmaxp, pw_bf, projb, out);
}

// Round 11
// 195.226 us; speedup vs baseline: 1.1824x; 1.1824x over previous
//
#include <hip/hip_runtime.h>
#include <hip/hip_bf16.h>

typedef unsigned short u16;
typedef unsigned int u32;
typedef __attribute__((ext_vector_type(8))) short short8;   // 8 bf16 (4 VGPRs) MFMA operand
typedef __attribute__((ext_vector_type(4))) float f32x4;    // MFMA 16x16 accumulator

#define T_TOK 32768
#define SCALE_ATT 0.17677669529663687f   // 32^-0.5

__device__ __forceinline__ u16 f2bf(float f){
  u32 u = __float_as_uint(f);
  u32 r = u + 0x7fffu + ((u >> 16) & 1u);   // RTN-even
  return (u16)(r >> 16);
}
__device__ __forceinline__ float bf2f(u16 h){
  return __uint_as_float(((u32)h) << 16);
}

// XCD-chunked bijective block swizzle (nwg % 8 == 0): consecutive logical
// blocks land on the SAME XCD so shared operand panels hit its private L2.
__device__ __forceinline__ int xcd_swz(int flat, int nwg){
  return (flat & 7) * (nwg >> 3) + (flat >> 3);
}

// async global->LDS, 16B per lane. Dest = wave-uniform base + lane*16 (HW rule,
// m104/m108); global src is per-lane.
__device__ __forceinline__ void gl16(const u16* g, u16* l){
  __builtin_amdgcn_global_load_lds(
      (const __attribute__((address_space(1))) u32*)g,
      (__attribute__((address_space(3))) u32*)l, 16, 0, 0);
}

// ---------------- tiny prep: w1 fp32 -> (hi,lo) bf16 split, ONCE ------------
// R15: was recomputed per router block (512x redundant L2 reads + split VALU).
__global__ __launch_bounds__(256) void k_prep_w1(
    const float* __restrict__ rw1, u16* __restrict__ w1h, u16* __restrict__ w1l)
{
  int i = blockIdx.x * 256 + threadIdx.x;       // < 8192 float4
  float4 v = ((const float4*)rw1)[i];
  ushort4 h, l;
  h.x = f2bf(v.x); h.y = f2bf(v.y); h.z = f2bf(v.z); h.w = f2bf(v.w);
  l.x = f2bf(v.x - bf2f(h.x)); l.y = f2bf(v.y - bf2f(h.y));
  l.z = f2bf(v.z - bf2f(h.z)); l.w = f2bf(v.w - bf2f(h.w));
  ((ushort4*)w1h)[i] = h;
  ((ushort4*)w1l)[i] = l;
}

// ---------------- MFMA router (split-bf16 "bf16x3") + fused weight cvt ------
// blocks [0,512): router: h = relu(x@w1^T+b1) via MFMA with x,w1 as bf16
// (hi,lo) pairs -> logit err ~1e-6 << top-2 gap. w1 pre-split (k_prep_w1);
// x split in regs. Global loads software-pipelined one kt ahead (R13).
// Per-block expert histogram written to hist[block][8] (R15).
// blocks [512,2560): bf16 conversion of qkv_w / proj_w (BW-bound, overlaps).
__global__ __launch_bounds__(256) void k_router(
    const float* __restrict__ x, const u16* __restrict__ w1h, const u16* __restrict__ w1l,
    const float* __restrict__ b1, const float* __restrict__ w2, const float* __restrict__ b2,
    int* __restrict__ routes, float* __restrict__ pmax, int* __restrict__ hist,
    u16* __restrict__ x_bf,
    const float* __restrict__ qkvw, u16* __restrict__ qw_bf,
    const float* __restrict__ projw, u16* __restrict__ pw_bf)
{
  __shared__ __align__(16) char smem[64*132*4];   // 33792 B
  int tid = threadIdx.x;

  if (blockIdx.x >= 512){                 // ---- weight cvt section ----
    int b = blockIdx.x - 512;
    if (b < 1536){
      int i = b * 256 + tid;                       // < 393216 float4
      float4 v = ((const float4*)qkvw)[i];
      ushort4 o;
      o.x = f2bf(v.x); o.y = f2bf(v.y); o.z = f2bf(v.z); o.w = f2bf(v.w);
      ((ushort4*)qw_bf)[i] = o;
    } else {
      int i = (b - 1536) * 256 + tid;              // < 131072 float4
      float4 v = ((const float4*)projw)[i];
      ushort4 o;
      o.x = f2bf(v.x); o.y = f2bf(v.y); o.z = f2bf(v.z); o.w = f2bf(v.w);
      ((ushort4*)pw_bf)[i] = o;
    }
    return;
  }

  u16* Ah = (u16*)smem;          // 64 x 40
  u16* Al = Ah + 2560;           // 64 x 40
  u16* Bh = Al + 2560;           // 128 x 40
  u16* Bl = Bh + 5120;           // 128 x 40
  float* Hs = (float*)smem;      // overlay after MFMA: 64 x 132
  __shared__ int lhist[8];

  int t0 = blockIdx.x * 64;
  int wv = tid >> 6, lane = tid & 63, quad = lane >> 4, l16 = lane & 15;
  if (tid < 8) lhist[tid] = 0;

  int arow = tid >> 2, acg = tid & 3;        // A staging: 64 rows x 4 col-groups of 8
  int brow = tid >> 1, bhalf = tid & 1;      // B staging: 128 rows x 2 halves of 16

  f32x4 acc[4][2];
  #pragma unroll
  for (int i = 0; i < 4; ++i)
    #pragma unroll
    for (int j = 0; j < 2; ++j)
      #pragma unroll
      for (int rr = 0; rr < 4; ++rr) acc[i][j][rr] = 0.f;

  const float* gx_base = x + (size_t)(t0 + arow) * 256 + acg * 8;
  u16* gxb_base = x_bf + (size_t)(t0 + arow) * 256 + acg * 8;
  const u16* gwh_base = w1h + (size_t)brow * 256 + bhalf * 16;
  const u16* gwl_base = w1l + (size_t)brow * 256 + bhalf * 16;

  // prologue: loads for kt=0
  float4 v0 = *(const float4*)gx_base;
  float4 v1 = *(const float4*)(gx_base + 4);
  uint4 wh0 = *(const uint4*)(gwh_base);
  uint4 wh1 = *(const uint4*)(gwh_base + 8);
  uint4 wl0 = *(const uint4*)(gwl_base);
  uint4 wl1 = *(const uint4*)(gwl_base + 8);

  for (int kt = 0; kt < 8; ++kt){
    ushort4 h0, h1, l0, l1;
    h0.x = f2bf(v0.x); h0.y = f2bf(v0.y); h0.z = f2bf(v0.z); h0.w = f2bf(v0.w);
    h1.x = f2bf(v1.x); h1.y = f2bf(v1.y); h1.z = f2bf(v1.z); h1.w = f2bf(v1.w);
    l0.x = f2bf(v0.x - bf2f(h0.x)); l0.y = f2bf(v0.y - bf2f(h0.y));
    l0.z = f2bf(v0.z - bf2f(h0.z)); l0.w = f2bf(v0.w - bf2f(h0.w));
    l1.x = f2bf(v1.x - bf2f(h1.x)); l1.y = f2bf(v1.y - bf2f(h1.y));
    l1.z = f2bf(v1.z - bf2f(h1.z)); l1.w = f2bf(v1.w - bf2f(h1.w));
    *(ushort4*)(gxb_base + kt*32)     = h0;
    *(ushort4*)(gxb_base + kt*32 + 4) = h1;
    __syncthreads();
    *(ushort4*)&Ah[arow*40 + acg*8    ] = h0;
    *(ushort4*)&Ah[arow*40 + acg*8 + 4] = h1;
    *(ushort4*)&Al[arow*40 + acg*8    ] = l0;
    *(ushort4*)&Al[arow*40 + acg*8 + 4] = l1;
    *(uint4*)&Bh[brow*40 + bhalf*16    ] = wh0;
    *(uint4*)&Bh[brow*40 + bhalf*16 + 8] = wh1;
    *(uint4*)&Bl[brow*40 + bhalf*16    ] = wl0;
    *(uint4*)&Bl[brow*40 + bhalf*16 + 8] = wl1;
    __syncthreads();
    if (kt < 7){                       // prefetch kt+1: latency hides under MFMA
      v0  = *(const float4*)(gx_base + (kt+1)*32);
      v1  = *(const float4*)(gx_base + (kt+1)*32 + 4);
      wh0 = *(const uint4*)(gwh_base + (kt+1)*32);
      wh1 = *(const uint4*)(gwh_base + (kt+1)*32 + 8);
      wl0 = *(const uint4*)(gwl_base + (kt+1)*32);
      wl1 = *(const uint4*)(gwl_base + (kt+1)*32 + 8);
    }
    short8 ah[4], al[4], bhf[2], blf[2];
    #pragma unroll
    for (int i = 0; i < 4; ++i){
      ah[i] = *(const short8*)&Ah[(i*16 + l16)*40 + quad*8];
      al[i] = *(const short8*)&Al[(i*16 + l16)*40 + quad*8];
    }
    #pragma unroll
    for (int j = 0; j < 2; ++j){
      bhf[j] = *(const short8*)&Bh[(wv*32 + j*16 + l16)*40 + quad*8];
      blf[j] = *(const short8*)&Bl[(wv*32 + j*16 + l16)*40 + quad*8];
    }
    #pragma unroll
    for (int i = 0; i < 4; ++i)
      #pragma unroll
      for (int j = 0; j < 2; ++j){
        acc[i][j] = __builtin_amdgcn_mfma_f32_16x16x32_bf16(ah[i], bhf[j], acc[i][j], 0, 0, 0);
        acc[i][j] = __builtin_amdgcn_mfma_f32_16x16x32_bf16(ah[i], blf[j], acc[i][j], 0, 0, 0);
        acc[i][j] = __builtin_amdgcn_mfma_f32_16x16x32_bf16(al[i], bhf[j], acc[i][j], 0, 0, 0);
      }
  }
  __syncthreads();   // all frag reads done before Hs overlay

  #pragma unroll
  for (int i = 0; i < 4; ++i)
    #pragma unroll
    for (int j = 0; j < 2; ++j){
      int col = wv*32 + j*16 + l16;
      float bb = b1[col];
      #pragma unroll
      for (int rr = 0; rr < 4; ++rr){
        float h = acc[i][j][rr] + bb;
        Hs[(i*16 + quad*4 + rr)*132 + col] = h > 0.f ? h : 0.f;
      }
    }
  __syncthreads();

  // logits + softmax: 8 lanes per token (e = tid&7), 32 tokens/pass (fp32)
  #pragma unroll
  for (int pass = 0; pass < 2; ++pass){
    int mtok = (tid >> 3) + pass * 32;
    int e = tid & 7;
    const float4* w2r = (const float4*)(w2 + e * 128);
    float l = b2[e];
    #pragma unroll
    for (int k4 = 0; k4 < 32; ++k4){
      float4 w = w2r[k4];
      int k = k4 * 4;
      l = fmaf(Hs[mtok*132+k  ], w.x, l);
      l = fmaf(Hs[mtok*132+k+1], w.y, l);
      l = fmaf(Hs[mtok*132+k+2], w.z, l);
      l = fmaf(Hs[mtok*132+k+3], w.w, l);
    }
    float mv = l; int mi = e;
    #pragma unroll
    for (int off = 1; off < 8; off <<= 1){
      float ov = __shfl_xor(mv, off, 64);
      int   oi = __shfl_xor(mi, off, 64);
      if (ov > mv || (ov == mv && oi < mi)){ mv = ov; mi = oi; }
    }
    float sum = expf(l - mv);
    #pragma unroll
    for (int off = 1; off < 8; off <<= 1) sum += __shfl_xor(sum, off, 64);
    if (e == 0){
      int t = t0 + mtok;
      routes[t] = mi;
      pmax[t] = 1.0f / sum;
      atomicAdd(&lhist[mi], 1);
    }
  }
  __syncthreads();
  if (tid < 8) hist[blockIdx.x * 8 + tid] = lhist[tid];
}

// ---------------- deterministic scatter (R15) ----------------
__global__ __launch_bounds__(256) void k_scatter(
    const int* __restrict__ routes, const int* __restrict__ hist,
    int* __restrict__ sorted, int* __restrict__ rank, int* __restrict__ offs)
{
  __shared__ int s_tot[8], s_pre[8], so[9], lc[8];
  int tid = threadIdx.x, b = blockIdx.x;
  if (tid < 8){ s_tot[tid] = 0; s_pre[tid] = 0; lc[tid] = 0; }
  __syncthreads();
  int e8 = tid & 7, r0 = tid >> 3;           // 32 rb-strides per expert
  int tot = 0, pre = 0;
  for (int rb = r0; rb < 512; rb += 32){
    int v = hist[rb * 8 + e8];
    tot += v;
    if (rb < b * 4) pre += v;                // router block rb covers tokens [64rb,64rb+64)
  }
  atomicAdd(&s_tot[e8], tot);
  atomicAdd(&s_pre[e8], pre);
  __syncthreads();
  if (tid == 0){
    int o = 0; so[0] = 0;
    #pragma unroll
    for (int e = 0; e < 8; ++e){ o += ((s_tot[e] + 127) >> 7) << 7; so[e+1] = o; }
  }
  __syncthreads();
  int t = b * 256 + tid;
  int e = routes[t];
  int rl = atomicAdd(&lc[e], 1);
  int pos = so[e] + s_pre[e] + rl;
  sorted[pos] = t;
  rank[t] = pos;
  if (b == 0){
    if (tid < 9) offs[tid] = so[tid];
    #pragma unroll
    for (int e2 = 0; e2 < 8; ++e2)
      for (int i = so[e2] + s_tot[e2] + tid; i < so[e2+1]; i += 256) sorted[i] = -1;
  }
}

// ---------------- grouped MoE GEMM: out[t] = A_sorted @ W[e]^T + bias[e] ----------------
// R14: counted-vmcnt depth-2 pipeline (T3/T4). 3 LDS buffers; stage kt+2 each
// iteration; per-wave `s_waitcnt vmcnt(4)` (NOT drain-0) + raw s_barrier keeps
// 8 DMA loads in flight across barriers. Chunk XOR swizzle keeps ds_read_b128
// conflict-free (verified 0 in R4). Epilogue (!PROJ) applies 2D RoPE, folds
// SCALE_ATT into Q, writes head-major windowed layout [sel][head][win][n][32ch].
template<int NOUT, bool PROJ, int NB, int NWG>
__global__ __launch_bounds__(256) void k_gemm(
    const u16* __restrict__ A, const u16* __restrict__ W,
    const float* __restrict__ bias, const int* __restrict__ sidx,
    const int* __restrict__ offs, const float* __restrict__ pmax,
    u16* __restrict__ outb, float* __restrict__ outf)
{
  __shared__ __align__(1024) u16 As[3][4096];   // [buf][row*32 + slot*8], 8KB/buf
  __shared__ __align__(1024) u16 Bs[3][4096];
  int tid = threadIdx.x;
  int flat = blockIdx.y * NB + blockIdx.x;     // hw dispatch order (x fastest)
  int logical = xcd_swz(flat, NWG);
  int m0 = (logical / NB) * 128;
  int n0 = (logical % NB) * 128;
  int total = offs[8];
  if (m0 >= total) return;
  int e = 0;
  #pragma unroll
  for (int i = 1; i < 8; ++i) if (m0 >= offs[i]) e = i;

  int wv = tid >> 6, lane = tid & 63, quad = lane >> 4, l16 = lane & 15;
  int wrow = (wv >> 1) * 64, wcol = (wv & 1) * 64;

  // staging geometry: wave wv fills rows [wv*16, wv*16+16) (instr0) and +64
  // (instr1); lane l: row = wv*16 + (l>>2), LDS chunk slot = l&3. The global
  // chunk fetched for slot s of row r is s ^ ((r>>1)&3)  (involution).
  int srow = wv*16 + (lane >> 2);
  int cg = (lane & 3) ^ ((srow >> 1) & 3);     // global chunk to fetch
  const u16 *ag0, *ag1;
  if (PROJ){
    ag0 = A + (size_t)(m0 + srow) * 256 + cg * 8;
    ag1 = A + (size_t)(m0 + srow + 64) * 256 + cg * 8;
  } else {
    int tA0 = sidx[m0 + srow];      if (tA0 < 0) tA0 = 0;   // row discarded in epilogue
    int tA1 = sidx[m0 + srow + 64]; if (tA1 < 0) tA1 = 0;
    ag0 = A + (size_t)tA0 * 256 + cg * 8;
    ag1 = A + (size_t)tA1 * 256 + cg * 8;
  }
  int pc = (srow >> 4) + (srow & 15) * 4;      // permuted col within 64-half
  const u16* bg0 = W + ((size_t)e * NOUT + n0 + pc) * 256 + cg * 8;
  const u16* bg1 = W + ((size_t)e * NOUT + n0 + 64 + pc) * 256 + cg * 8;

  f32x4 acc[4][4];
  #pragma unroll
  for (int i = 0; i < 4; ++i)
    #pragma unroll
    for (int j = 0; j < 4; ++j)
      #pragma unroll
      for (int r = 0; r < 4; ++r) acc[i][j][r] = 0.f;

  int qsw8 = (quad ^ ((l16 >> 1) & 3)) * 8;    // swizzled read slot (elems)

#define STAGE_KT(kt, buf) do { \
    u16* a_lo = (u16*)((char*)&As[(buf)][0] + wv*1024); \
    u16* b_lo = (u16*)((char*)&Bs[(buf)][0] + wv*1024); \
    gl16(ag0 + (kt)*32, a_lo); \
    gl16(ag1 + (kt)*32, (u16*)((char*)a_lo + 4096)); \
    gl16(bg0 + (kt)*32, b_lo); \
    gl16(bg1 + (kt)*32, (u16*)((char*)b_lo + 4096)); \
  } while(0)

  // prologue: stage kt 0 and 1 (8 loads in flight)
  STAGE_KT(0, 0);
  STAGE_KT(1, 1);

  #pragma unroll
  for (int kt = 0; kt < 8; ++kt){
    const int cur = kt % 3;
    // wait MY stage-kt loads (leave the 4 newer in flight), then align waves.
    if (kt < 7) asm volatile("s_waitcnt vmcnt(4) lgkmcnt(0)" ::: "memory");
    else        asm volatile("s_waitcnt vmcnt(0) lgkmcnt(0)" ::: "memory");
    __builtin_amdgcn_sched_barrier(0);
    __builtin_amdgcn_s_barrier();
    __builtin_amdgcn_sched_barrier(0);
    if (kt < 6) STAGE_KT(kt+2, (kt+2)%3);   // buf (kt+2)%3 == (kt-1)%3: all
                                            // waves done reading it (barrier)
    short8 af[4], bfv[4];
    #pragma unroll
    for (int i = 0; i < 4; ++i)
      af[i] = *(const short8*)&As[cur][(wrow + i*16 + l16)*32 + qsw8];
    #pragma unroll
    for (int j = 0; j < 4; ++j)
      bfv[j] = *(const short8*)&Bs[cur][(wcol + j*16 + l16)*32 + qsw8];
    #pragma unroll
    for (int i = 0; i < 4; ++i)
      #pragma unroll
      for (int j = 0; j < 4; ++j)
        acc[i][j] = __builtin_amdgcn_mfma_f32_16x16x32_bf16(af[i], bfv[j], acc[i][j], 0, 0, 0);
  }
#undef STAGE_KT

  // epilogue: frag j of lane l16 = output col n0+wcol+l16*4+j (contiguous)
  float4 bj4 = *(const float4*)&bias[e*NOUT + n0 + wcol + l16*4];
  if (PROJ){
    #pragma unroll
    for (int i = 0; i < 4; ++i){
      #pragma unroll
      for (int ri = 0; ri < 4; ++ri){
        int row = wrow + i*16 + quad*4 + ri;        // C/D: row=quad*4+reg [m89]
        int t = sidx[m0 + row];
        if (t < 0) continue;
        float pm = pmax[t];
        float4 ov;
        ov.x = (acc[i][0][ri] + bj4.x) * pm;
        ov.y = (acc[i][1][ri] + bj4.y) * pm;
        ov.z = (acc[i][2][ri] + bj4.z) * pm;
        ov.w = (acc[i][3][ri] + bj4.w) * pm;
        *(float4*)&outf[(size_t)t * NOUT + n0 + wcol + l16*4] = ov;
      }
    }
  } else {
    // qkv: cols [0,256)=Q (rotate + scale), [256,512)=K (rotate), [512,768)=V
    int col0 = n0 + wcol + l16*4;
    bool isqk = (col0 < 512);
    float inv0 = 0.f, inv1 = 0.f;
    float qsc = (col0 < 256) ? SCALE_ATT : 1.0f;
    if (isqk){
      int p0 = (col0 & 15) >> 1;                    // pair idx within half: 0,2,4,6
      inv0 = __expf(-1.1512925465f * (float)p0);    // 10000^(-p0/8)
      inv1 = inv0 * 0.31622776601683794f;           // * 10^-0.5 -> 10000^(-(p0+1)/8)
    }
    int sel  = col0 >> 8;                            // 0=Q 1=K 2=V
    int head = (col0 >> 5) & 7;
    int ch   = col0 & 31;                            // multiple of 4
    size_t hb = ((size_t)(sel * 8 + head) * 512) * 2048 + ch;
    #pragma unroll
    for (int i = 0; i < 4; ++i){
      #pragma unroll
      for (int ri = 0; ri < 4; ++ri){
        int row = wrow + i*16 + quad*4 + ri;
        int t = sidx[m0 + row];
        if (t < 0) continue;
        float vx = acc[i][0][ri] + bj4.x;
        float vy = acc[i][1][ri] + bj4.y;
        float vz = acc[i][2][ri] + bj4.z;
        float vw = acc[i][3][ri] + bj4.w;
        if (isqk){
          // token window coords: row half = (t>>6)&7, col half = t&7
          float pos = (float)((col0 & 16) ? (t & 7) : ((t >> 6) & 7));
          float a0r = pos * inv0, a1r = pos * inv1;
          float s0, c0s, s1, c1s;
          __sincosf(a0r, &s0, &c0s);
          __sincosf(a1r, &s1, &c1s);
          float r0 = (vx*c0s - vy*s0) * qsc;
          float r1 = (vx*s0 + vy*c0s) * qsc;
          float r2 = (vz*c1s - vw*s1) * qsc;
          float r3 = (vz*s1 + vw*c1s) * qsc;
          vx = r0; vy = r1; vz = r2; vw = r3;
        }
        // head-major windowed address: win = b*64+wy*8+wx, n = iy*8+ix
        int win = (t >> 12) * 64 + ((t >> 9) & 7) * 8 + ((t >> 3) & 7);
        int n   = ((t >> 6) & 7) * 8 + (t & 7);
        uint2 ov;
        ov.x = (u32)f2bf(vx) | ((u32)f2bf(vy) << 16);
        ov.y = (u32)f2bf(vz) | ((u32)f2bf(vw) << 16);
        *(uint2*)&outb[hb + (size_t)win * 2048 + n * 32] = ov;
      }
    }
  }
}

// ---------------- MFMA windowed attention (RoPE pre-applied in QKV GEMM) ----------------
// One 64-thread block per (head, window). qkv is head-major windowed, so every
// Q/K fragment load and V sweep is a fully-dense 1KB wave access. rank[] is
// prefetched at the top (broadcast loads hidden under QK). Row-sums via
// shfl_xor. LDS 13824B.
__global__ __launch_bounds__(64, 3) void k_attn(const u16* __restrict__ qkv,
                                                const int* __restrict__ rank,
                                                u16* __restrict__ attn_s)
{
  __shared__ __align__(16) u16 Ps[64*72];   // P bf16, permuted cols, stride 72
  __shared__ __align__(16) u16 Vt[32*72];   // V^T: Vt[d][pi(n)]

  int lane = threadIdx.x;
  int quad = lane >> 4, l16 = lane & 15;
  int wh = xcd_swz(blockIdx.x, 4096);
  int head = wh >> 9, win = wh & 511;        // head-major: consecutive blocks walk wins
  int b = win >> 6, wy = (win >> 3) & 7, wx = win & 7;
  int tb = b*4096 + wy*512 + wx*8;           // token(n) = tb + (n>>3)*64 + (n&7)

  const u16* qbase = qkv + (size_t)(head * 512 + win) * 2048;
  const u16* kbase = qbase + (size_t)8 * 512 * 2048;
  const u16* vbase = qbase + (size_t)16 * 512 * 2048;

  // rank prefetch: 16 broadcast loads, latency hidden under QK^T
  int rk[4][4];
  #pragma unroll
  for (int i = 0; i < 4; ++i)
    #pragma unroll
    for (int rr = 0; rr < 4; ++rr){
      int m = i*16 + quad*4 + rr;
      rk[i][rr] = rank[tb + (m >> 3) * 64 + (m & 7)];
    }

  // Q/K frags: wave covers 1KB contiguous per load (token n = i*16+l16, ch quad*8)
  short8 qf[4], kf[4];
  #pragma unroll
  for (int i = 0; i < 4; ++i){
    qf[i] = *(const short8*)(qbase + (i*16 + l16)*32 + quad*8);
    kf[i] = *(const short8*)(kbase + (i*16 + l16)*32 + quad*8);
  }
  // V: 4 x 1KB dense sweeps; lane holds token n = h*16+l16, ch quad*8..+7
  uint4 va[4];
  #pragma unroll
  for (int h = 0; h < 4; ++h)
    va[h] = *(const uint4*)(vbase + h*512 + l16*32 + quad*8);

  // S = Q K^T (scale already folded into Q)
  f32x4 sa[4][4];
  #pragma unroll
  for (int i = 0; i < 4; ++i)
    #pragma unroll
    for (int j = 0; j < 4; ++j){
      #pragma unroll
      for (int rr = 0; rr < 4; ++rr) sa[i][j][rr] = 0.f;
      sa[i][j] = __builtin_amdgcn_mfma_f32_16x16x32_bf16(qf[i], kf[j], sa[i][j], 0, 0, 0);
    }

  // P = exp(S) -> bf16 -> Ps (permuted col pi(n) = (n&15)*4 + (n>>4));
  // row-sum accumulated per (i,rr) then shfl-reduced over l16 (cols).
  f32x4 rs[4];
  #pragma unroll
  for (int i = 0; i < 4; ++i)
    #pragma unroll
    for (int rr = 0; rr < 4; ++rr){
      float e0 = __expf(sa[i][0][rr]);
      float e1 = __expf(sa[i][1][rr]);
      float e2 = __expf(sa[i][2][rr]);
      float e3 = __expf(sa[i][3][rr]);
      rs[i][rr] = (e0 + e1) + (e2 + e3);
      uint2 pk;
      pk.x = (u32)f2bf(e0) | ((u32)f2bf(e1) << 16);
      pk.y = (u32)f2bf(e2) | ((u32)f2bf(e3) << 16);
      *(uint2*)&Ps[(i*16 + quad*4 + rr)*72 + l16*4] = pk;
    }
  #pragma unroll
  for (int i = 0; i < 4; ++i)
    #pragma unroll
    for (int rr = 0; rr < 4; ++rr){
      #pragma unroll
      for (int off = 1; off < 16; off <<= 1)
        rs[i][rr] += __shfl_xor(rs[i][rr], off, 64);
    }

  // stage V transposed+permuted: Vt[d][pi(n)] = V[n][d]; pi(n) = l16*4 + h
  u32* vu = (u32*)va;
  #pragma unroll
  for (int h = 0; h < 4; ++h){
    int pn = l16 * 4 + h;
    #pragma unroll
    for (int w = 0; w < 4; ++w){
      u32 vv = vu[h*4 + w];
      Vt[(quad*8 + 2*w    )*72 + pn] = (u16)(vv & 0xffff);
      Vt[(quad*8 + 2*w + 1)*72 + pn] = (u16)(vv >> 16);
    }
  }

  // PV: P A-frags from Ps, V B-frags from Vt (both in pi-space), 2 k-steps of 32.
  f32x4 oa[4][2];
  #pragma unroll
  for (int i = 0; i < 4; ++i)
    #pragma unroll
    for (int rr = 0; rr < 4; ++rr){ oa[i][0][rr] = 0.f; oa[i][1][rr] = 0.f; }
  #pragma unroll
  for (int ks = 0; ks < 2; ++ks){
    short8 vf0 = *(const short8*)&Vt[(     l16)*72 + ks*32 + quad*8];
    short8 vf1 = *(const short8*)&Vt[(16 + l16)*72 + ks*32 + quad*8];
    #pragma unroll
    for (int i = 0; i < 4; ++i){
      short8 pf = *(const short8*)&Ps[(i*16 + l16)*72 + ks*32 + quad*8];
      oa[i][0] = __builtin_amdgcn_mfma_f32_16x16x32_bf16(pf, vf0, oa[i][0], 0, 0, 0);
      oa[i][1] = __builtin_amdgcn_mfma_f32_16x16x32_bf16(pf, vf1, oa[i][1], 0, 0, 0);
    }
  }

  // epilogue: O[m][d] = oa/rowsum; store bf16 at sorted position rank[token]
  #pragma unroll
  for (int i = 0; i < 4; ++i)
    #pragma unroll
    for (int rr = 0; rr < 4; ++rr){
      float inv = __builtin_amdgcn_rcpf(rs[i][rr]);
      int pos = rk[i][rr];
      u16* op = attn_s + (size_t)pos * 256 + head * 32 + l16;
      op[0]  = f2bf(oa[i][0][rr] * inv);
      op[16] = f2bf(oa[i][1][rr] * inv);
    }
}

// ---------------- launch ----------------
extern "C" void kernel_launch(void* const* d_in, const int* in_sizes, int n_in,
                              void* d_out, int out_size, void* d_ws, size_t ws_size,
                              hipStream_t stream){
  const float* x     = (const float*)d_in[0];
  const float* rw1   = (const float*)d_in[1];
  const float* rb1   = (const float*)d_in[2];
  const float* rw2   = (const float*)d_in[3];
  const float* rb2   = (const float*)d_in[4];
  const float* qkvw  = (const float*)d_in[5];
  const float* qkvb  = (const float*)d_in[6];
  const float* projw = (const float*)d_in[7];
  const float* projb = (const float*)d_in[8];
  float* out = (float*)d_out;

  char* ws = (char*)d_ws;
  u16*   x_bf    = (u16*)(ws);                       // 16,777,216 B
  u16*   qkv_bf  = (u16*)(ws + 16777216);            // 50,331,648 B (head-major windowed)
  // shared region (disjoint lifetimes): w1 split (prep+router) -> attn_s
  // (attn + proj gemm). 17,301,504 B.
  u16*   w1h     = (u16*)(ws + 67108864);            //     65,536 B
  u16*   w1l     = w1h + 32768;                      //     65,536 B
  u16*   attn_s  = (u16*)(ws + 67108864);
  u16*   qw_bf   = (u16*)(ws + 84410368);            //  3,145,728 B
  u16*   pw_bf   = (u16*)(ws + 87556096);            //  1,048,576 B
  int*   routes  = (int*)(ws + 88604672);            //    131,072 B
  float* pmaxp   = (float*)(ws + 88735744);          //    131,072 B
  int*   sorted  = (int*)(ws + 88866816);            //    135,168 B (33792 slots)
  int*   rank    = (int*)(ws + 89001984);            //    131,072 B
  int*   hist    = (int*)(ws + 89133056);            //     16,384 B (512 x 8)
  int*   offs    = (int*)(ws + 89149440);            //         36 B

  k_prep_w1<<<32, 256, 0, stream>>>(rw1, w1h, w1l);
  k_router<<<2560, 256, 0, stream>>>(x, w1h, w1l, rb1, rw2, rb2, routes, pmaxp, hist,
                                     x_bf, qkvw, qw_bf, projw, pw_bf);
  k_scatter<<<128, 256, 0, stream>>>(routes, hist, sorted, rank, offs);
  k_gemm<768, false, 6, 1584><<<dim3(6, 264), 256, 0, stream>>>(
      x_bf, qw_bf, qkvb, sorted, offs, nullptr, qkv_bf, nullptr);
  k_attn<<<4096, 64, 0, stream>>>(qkv_bf, rank, attn_s);
  k_gemm<256, true, 2, 528><<<dim3(2, 264), 256, 0, stream>>>(
      attn_s, pw_bf, projb, sorted, offs, pmaxp, nullptr, out);
}